// Round 7
// baseline (248.320 us; speedup 1.0000x reference)
//
#include <hip/hip_runtime.h>

// CTC batch loss (keras ctc_batch_cost), B=256, T=512, C=256, U=64.
// Single kernel, one 64-lane wave per batch element. Lane l owns extended
// states 2l (blank) and 2l+1 (label l); lane 63 also owns state 128 (its
// s-1 neighbor is its own odd register -> one DPP shr per step).
// Linear-domain recurrence + wave-uniform power-of-2 rescale every 8 steps.
//
// Data path (all within ONE wave, no __syncthreads):
//   - chunked register pipeline: 8-row chunks, double-buffered float4[8]
//     (each row = 1 KB = 64 lanes x dwordx4, perfectly coalesced);
//     chunk k+1's 8 loads issued before chunk k's steps, sched_barrier(0)
//     pins them there (16 rows = 16 KB in flight per wave).
//   - 8-slot LDS ring (8 KB): at step t write row t+5 (from regs), gather
//     row t+4 (label + blank) into pf regs, consume row t from pf regs.
//     1-step write->read gap avoids lgkm stalls; 4-step pf lookahead covers
//     LDS latency. Slot indices are compile-time (row r -> slot r%8).
// Expected bound: HBM stream of y_pred (134 MB) at ~1 KB / ~100 cyc / step.

constexpr int B = 256, T = 512, C = 256, U = 64;
#define EPSF 1e-7f

__device__ __forceinline__ float dpp_wave_shr1(float x) {
    // previous lane's value; lane 0 -> 0 (bound_ctrl)
    return __int_as_float(__builtin_amdgcn_update_dpp(
        0, __float_as_int(x), 0x138, 0xf, 0xf, true));
}

#define DPPMAX(ctrl)                                                      \
    {                                                                     \
        float x_ = __int_as_float(__builtin_amdgcn_update_dpp(            \
            0, __float_as_int(m_), (ctrl), 0xf, 0xf, true));              \
        m_ = fmaxf(m_, x_);                                               \
    }

#define RESCALE()                                                         \
    {                                                                     \
        float m_ = fmaxf(fmaxf(a_even, a_odd), a_top);                    \
        DPPMAX(0x111) DPPMAX(0x112) DPPMAX(0x114) DPPMAX(0x118)           \
        DPPMAX(0x142) DPPMAX(0x143)                                       \
        const float mx_ = __int_as_float(                                 \
            __builtin_amdgcn_readlane(__float_as_int(m_), 63));           \
        int e_ = (__float_as_int(mx_) >> 23) & 0xff;                      \
        int k_ = 187 - e_;                                                \
        k_ = k_ > 127 ? 127 : k_;                                         \
        const float s_ = __int_as_float((k_ + 127) << 23);                \
        a_even *= s_; a_odd *= s_; a_top *= s_;                           \
        esum += k_;                                                       \
    }

// One 8-step chunk kk (t = 8*kk + i). CUR holds rows 8kk..8kk+7; NXT gets
// rows 8(kk+1)..8(kk+1)+7. LDS write at step i: row t+5 (i<3: CUR[i+5],
// else NXT[i-3]); gather row t+4 (slot (i+4)%8).
#define CHUNK(CUR, NXT, kexpr)                                            \
    {                                                                     \
        const int k_ = (kexpr);                                           \
        if (k_ < 63) {                                                    \
            const float4* np_ = rp4 + (size_t)(k_ + 1) * 512;             \
            _Pragma("unroll")                                             \
            for (int j = 0; j < 8; ++j) NXT[j] = np_[j * 64];             \
        }                                                                 \
        __builtin_amdgcn_sched_barrier(0);                                \
        _Pragma("unroll")                                                 \
        for (int i = 0; i < 8; ++i) {                                     \
            const float pb = pblk[i & 3] + EPSF;   /* row t */            \
            const float pl = plab[i & 3] + EPSF;                          \
            if (i < 3) {                           /* write row t+5 */    \
                ((float4*)&lds[((i + 5) & 7) * C])[lane] = CUR[i + 5];    \
            } else if (k_ < 63) {                                         \
                ((float4*)&lds[((i + 5) & 7) * C])[lane] = NXT[i - 3];    \
            }                                                             \
            if (i < 4 || k_ < 63) {                /* gather row t+4 */   \
                plab[i & 3] = lds[((i + 4) & 7) * C + label];             \
                pblk[i & 3] = lds[((i + 4) & 7) * C + (C - 1)];           \
            }                                                             \
            const float po = dpp_wave_shr1(a_odd); /* alpha[2l-1] */      \
            const float skp = skip_ok ? po : 0.f;                         \
            const float ne = (a_even + po) * pb;                          \
            const float no = (a_even + a_odd + skp) * pl;                 \
            const float nt = (a_top + a_odd) * pb;                        \
            a_even = ne; a_odd = no; a_top = nt;                          \
            if (i == 7) RESCALE();                                        \
        }                                                                 \
    }

__global__ __launch_bounds__(64) void ctc_kernel(const int* __restrict__ y_true,
                                                 const float* __restrict__ y_pred,
                                                 float* __restrict__ out) {
    __shared__ float lds[8 * C];                  // 8-row ring, 8 KB
    const int b = blockIdx.x;
    const int lane = threadIdx.x;
    const int label = y_true[b * U + lane];
    const int label_prev = __shfl_up(label, 1);
    const bool skip_ok = (lane > 0) && (label != label_prev);
    // rp4[r*64] = lane's float4 of row r
    const float4* __restrict__ rp4 =
        (const float4*)(y_pred + (size_t)b * T * C) + lane;

    float4 bufA[8], bufB[8];
#pragma unroll
    for (int j = 0; j < 8; ++j) bufA[j] = rp4[j * 64];   // chunk 0
#pragma unroll
    for (int j = 0; j < 5; ++j)                          // rows 0..4 -> LDS
        ((float4*)&lds[j * C])[lane] = bufA[j];
    float plab[4], pblk[4];
#pragma unroll
    for (int j = 0; j < 4; ++j) {                        // pf rows 0..3
        plab[j] = lds[j * C + label];
        pblk[j] = lds[j * C + (C - 1)];
    }

    // Seed so applying the recurrence at t=0 yields alpha0 exactly.
    float a_even = (lane == 0) ? 1.f : 0.f, a_odd = 0.f, a_top = 0.f;
    int esum = 0;

#pragma unroll 1
    for (int kk = 0; kk < 64; kk += 2) {
        CHUNK(bufA, bufB, kk);
        CHUNK(bufB, bufA, kk + 1);
    }

    // loss = -ln(alpha[128] + alpha[127]); stored = true * 2^esum
    if (lane == 63)
        out[b] = -logf(a_top + a_odd) + (float)esum * 0.69314718055994531f;
}

extern "C" void kernel_launch(void* const* d_in, const int* in_sizes, int n_in,
                              void* d_out, int out_size, void* d_ws, size_t ws_size,
                              hipStream_t stream) {
    const int* y_true   = (const int*)d_in[0];
    const float* y_pred = (const float*)d_in[1];
    float* out = (float*)d_out;
    hipLaunchKernelGGL(ctc_kernel, dim3(B), dim3(64), 0, stream,
                       y_true, y_pred, out);
}

// Round 8
// 210.654 us; speedup vs baseline: 1.1788x; 1.1788x over previous
//
#include <hip/hip_runtime.h>

// CTC batch loss (keras ctc_batch_cost), B=256, T=512, C=256, U=64.
// Two-phase. Lesson from R1/R4/R7: one wave can't keep enough lines in
// flight to hide load latency on the serial chain -> split BW from latency.
//
// Phase 1 gather_kernel (1024 blk x 256 thr): parallel gather-transpose.
//   Wave w of block g handles batch g>>2, rows (g&3)*128 + w*32 .. +31.
//   Per row: one coalesced dwordx4/lane (1 KB), bounce via private 2-row
//   LDS buffer, write lab[b][t][l] = row[label_l]+EPS (256 B coalesced,
//   aligned) and blk[b][t] = row[255]+EPS. TLP (4096 waves) hides latency;
//   bounded by 134 MB read + 34 MB write.
//
// Phase 2 chain_compact (256 blk x 64 thr): serial recurrence, one wave per
//   batch. Lane l owns states 2l, 2l+1; lane 63 also state 128. Linear
//   domain + wave-uniform power-of-2 rescale every 8 steps. Per step: ONE
//   dword load (lane l -> lab[b][t][l]); blanks ONE load per 32 steps
//   (lanes 0..31, readlane broadcast). 32-step chunked register double
//   buffering -> ~33 outstanding loads, covers L2 latency.
//
// Fallback if ws too small: direct-gather chain (R4 structure).

constexpr int B = 256, T = 512, C = 256, U = 64;
constexpr int CH = 32;                     // phase-2 chunk (steps)
#define EPSF 1e-7f

__device__ __forceinline__ float dpp_wave_shr1(float x) {
    // previous lane's value; lane 0 -> 0 (bound_ctrl)
    return __int_as_float(__builtin_amdgcn_update_dpp(
        0, __float_as_int(x), 0x138, 0xf, 0xf, true));
}

#define DPPMAX(ctrl)                                                      \
    {                                                                     \
        float x_ = __int_as_float(__builtin_amdgcn_update_dpp(            \
            0, __float_as_int(m_), (ctrl), 0xf, 0xf, true));              \
        m_ = fmaxf(m_, x_);                                               \
    }

#define RESCALE()                                                         \
    {                                                                     \
        float m_ = fmaxf(fmaxf(a_even, a_odd), a_top);                    \
        DPPMAX(0x111) DPPMAX(0x112) DPPMAX(0x114) DPPMAX(0x118)           \
        DPPMAX(0x142) DPPMAX(0x143)                                       \
        const float mx_ = __int_as_float(                                 \
            __builtin_amdgcn_readlane(__float_as_int(m_), 63));           \
        int e_ = (__float_as_int(mx_) >> 23) & 0xff;                      \
        int k_ = 187 - e_;                                                \
        k_ = k_ > 127 ? 127 : k_;                                         \
        const float s_ = __int_as_float((k_ + 127) << 23);                \
        a_even *= s_; a_odd *= s_; a_top *= s_;                           \
        esum += k_;                                                       \
    }

// ---------------- Phase 1: gather-transpose ----------------
__global__ __launch_bounds__(256) void gather_kernel(const int* __restrict__ y_true,
                                                     const float* __restrict__ y_pred,
                                                     float* __restrict__ lab,
                                                     float* __restrict__ blk) {
    __shared__ float buf[4][2][C];            // per-wave 2-row buffer (8 KB)
    const int lane = threadIdx.x & 63;
    const int w = threadIdx.x >> 6;
    const int g = blockIdx.x;                 // 1024 blocks
    const int b = g >> 2;
    const int r0 = (g & 3) * 128 + w * 32;    // 32 rows per wave
    const int lb = y_true[b * U + lane];
    const float4* __restrict__ rp4 =
        (const float4*)(y_pred + (size_t)b * T * C) + lane;
    float* __restrict__ lp = lab + (size_t)b * T * 64;
    float* __restrict__ bp = blk + (size_t)b * T;

    // 3-stage pipeline: load r+3 | LDS-write r+1 | gather+store r.
    float4 vA  = rp4[(size_t)r0 * 64];        // row r0   (to write this iter-1)
    float4 vA2 = rp4[(size_t)(r0 + 1) * 64];  // row r0+1
    ((float4*)&buf[w][0][0])[lane] = vA;      // row r0 -> buf0
    vA = vA2;
    vA2 = rp4[(size_t)(r0 + 2) * 64];
#pragma unroll
    for (int i = 0; i < 32; ++i) {
        float4 vB;
        if (i + 3 < 32) vB = rp4[(size_t)(r0 + i + 3) * 64];
        const int r = r0 + i;
        const float* bb = &buf[w][i & 1][0];
        lp[(size_t)r * 64 + lane] = bb[lb] + EPSF;      // coalesced 256 B
        if (lane == 0) bp[r] = bb[C - 1] + EPSF;        // blank
        if (i + 1 < 32) ((float4*)&buf[w][(i + 1) & 1][0])[lane] = vA;
        vA = vA2; vA2 = vB;
    }
}

// ---------------- Phase 2: serial chain on compact data ----------------
#define COMP32(LA, BV, cidx)                                              \
    {                                                                     \
        _Pragma("unroll")                                                 \
        for (int i = 0; i < CH; ++i) {                                    \
            const float pb = __int_as_float(                              \
                __builtin_amdgcn_readlane(__float_as_int(BV), i));        \
            const float pl = LA[i];                                       \
            const float po = dpp_wave_shr1(a_odd);                        \
            const float skp = skip_ok ? po : 0.f;                         \
            const float ne = (a_even + po) * pb;                          \
            const float no = (a_even + a_odd + skp) * pl;                 \
            const float nt = (a_top + a_odd) * pb;                        \
            a_even = ne; a_odd = no; a_top = nt;                          \
            if ((i & 7) == 7) RESCALE();                                  \
        }                                                                 \
    }

__global__ __launch_bounds__(64) void chain_compact(const int* __restrict__ y_true,
                                                    const float* __restrict__ lab,
                                                    const float* __restrict__ blk,
                                                    float* __restrict__ out) {
    const int b = blockIdx.x;
    const int lane = threadIdx.x;
    const int label = y_true[b * U + lane];
    const int label_prev = __shfl_up(label, 1);
    const bool skip_ok = (lane > 0) && (label != label_prev);
    const float* __restrict__ labp = lab + (size_t)b * T * 64 + lane;
    const float* __restrict__ bp = blk + (size_t)b * T;

    float la0[CH], la1[CH];
    float bv0, bv1;
#pragma unroll
    for (int i = 0; i < CH; ++i) la0[i] = labp[(size_t)i * 64];
    bv0 = bp[lane & 31];                      // blanks t = 0..31

    // Seed so applying the recurrence at t=0 yields alpha0 exactly.
    float a_even = (lane == 0) ? 1.f : 0.f, a_odd = 0.f, a_top = 0.f;
    int esum = 0;

    for (int c2 = 0; c2 < 8; ++c2) {          // 16 chunks, 2 per iter
        const int c = 2 * c2;
#pragma unroll
        for (int i = 0; i < CH; ++i)
            la1[i] = labp[((size_t)(c + 1) * CH + i) * 64];
        bv1 = bp[(c + 1) * CH + (lane & 31)];
        __builtin_amdgcn_sched_barrier(0);
        COMP32(la0, bv0, c);
        if (c2 < 7) {
#pragma unroll
            for (int i = 0; i < CH; ++i)
                la0[i] = labp[((size_t)(c + 2) * CH + i) * 64];
            bv0 = bp[(c + 2) * CH + (lane & 31)];
        }
        __builtin_amdgcn_sched_barrier(0);
        COMP32(la1, bv1, c + 1);
    }

    // loss = -ln(alpha[128] + alpha[127]); stored = true * 2^esum
    if (lane == 63)
        out[b] = -logf(a_top + a_odd) + (float)esum * 0.69314718055994531f;
}

// ---------------- Fallback: direct-gather chain (R4 structure) ----------
#define LOAD_CHUNK16(LA, BL, cidx)                                        \
    {                                                                     \
        _Pragma("unroll")                                                 \
        for (int i = 0; i < 16; ++i) {                                    \
            int t = (cidx) * 16 + i;                                      \
            t = t < T ? t : T - 1;                                        \
            LA[i] = labp[(size_t)t * C];                                  \
            BL[i] = blkp[(size_t)t * C];                                  \
        }                                                                 \
    }
#define COMP_CHUNK16(LA, BL, cidx)                                        \
    {                                                                     \
        _Pragma("unroll")                                                 \
        for (int i = 0; i < 16; ++i) {                                    \
            const int t = (cidx) * 16 + i;                                \
            const float pb = BL[i] + EPSF;                                \
            const float pl = LA[i] + EPSF;                                \
            const float po = dpp_wave_shr1(a_odd);                        \
            const float skp = skip_ok ? po : 0.f;                         \
            const float ne = (a_even + po) * pb;                          \
            const float no = (a_even + a_odd + skp) * pl;                 \
            const float nt = (a_top + a_odd) * pb;                        \
            a_even = ne; a_odd = no; a_top = nt;                          \
            if ((t & 7) == 7) RESCALE();                                  \
        }                                                                 \
    }

__global__ __launch_bounds__(64) void chain_direct(const int* __restrict__ y_true,
                                                   const float* __restrict__ y_pred,
                                                   float* __restrict__ out) {
    const int b = blockIdx.x;
    const int lane = threadIdx.x;
    const int label = y_true[b * U + lane];
    const int label_prev = __shfl_up(label, 1);
    const bool skip_ok = (lane > 0) && (label != label_prev);
    const float* __restrict__ base = y_pred + (size_t)b * T * C;
    const float* __restrict__ labp = base + label;
    const float* __restrict__ blkp = base + (C - 1);

    float a_even = (lane == 0) ? 1.f : 0.f, a_odd = 0.f, a_top = 0.f;
    int esum = 0;
    float la0[16], bl0[16], la1[16], bl1[16];
    LOAD_CHUNK16(la0, bl0, 0);
    for (int c2 = 0; c2 < 16; ++c2) {
        const int c = 2 * c2;
        LOAD_CHUNK16(la1, bl1, c + 1);
        __builtin_amdgcn_sched_barrier(0);
        COMP_CHUNK16(la0, bl0, c);
        if (c2 < 15) LOAD_CHUNK16(la0, bl0, c + 2);
        __builtin_amdgcn_sched_barrier(0);
        COMP_CHUNK16(la1, bl1, c + 1);
    }
    if (lane == 63)
        out[b] = -logf(a_top + a_odd) + (float)esum * 0.69314718055994531f;
}

extern "C" void kernel_launch(void* const* d_in, const int* in_sizes, int n_in,
                              void* d_out, int out_size, void* d_ws, size_t ws_size,
                              hipStream_t stream) {
    const int* y_true   = (const int*)d_in[0];
    const float* y_pred = (const float*)d_in[1];
    float* out = (float*)d_out;
    const size_t lab_elems = (size_t)B * T * 64;            // 33.55 MB
    const size_t need = (lab_elems + (size_t)B * T) * sizeof(float);
    if (ws_size >= need) {
        float* lab = (float*)d_ws;
        float* blk = lab + lab_elems;
        hipLaunchKernelGGL(gather_kernel, dim3(1024), dim3(256), 0, stream,
                           y_true, y_pred, lab, blk);
        hipLaunchKernelGGL(chain_compact, dim3(B), dim3(64), 0, stream,
                           y_true, lab, blk, out);
    } else {
        hipLaunchKernelGGL(chain_direct, dim3(B), dim3(64), 0, stream,
                           y_true, y_pred, out);
    }
}